// Round 9
// baseline (330.571 us; speedup 1.0000x reference)
//
#include <hip/hip_runtime.h>

#define NN 50000
#define EE 800000
#define FF 128
#define HH 256
#define CC 40
#define BN_EPS 1e-5f

typedef float f4 __attribute__((ext_vector_type(4)));
typedef _Float16 h8 __attribute__((ext_vector_type(8)));
typedef _Float16 h4 __attribute__((ext_vector_type(4)));

#define OFF_NODE 0            // 4*16 units
#define OFF_C1   32768        // 8*16 units
#define OFF_C2   98304
#define OFF_F1   163840
#define PW_HALVES 229376

#define SWZ(row, c2) ((c2) ^ (((row) & 7) << 4))

// ---------------- init: zero stats + degree ----------------
__global__ void k_init(float* __restrict__ stats, int* __restrict__ deg) {
    int i = blockIdx.x * blockDim.x + threadIdx.x;
    if (i < 2 * HH) stats[i] = 0.f;
    if (i < NN) deg[i] = 0;
}

// ---------------- prep: W_edge -> fp16 column-blocked [8][NN][32]  +  histogram ----------------
__global__ __launch_bounds__(256)
void k_prep(const float* __restrict__ W, _Float16* __restrict__ Wcb,
            const int* __restrict__ ei, int* __restrict__ deg) {
    const int gsz = gridDim.x * blockDim.x;
    const int i0 = blockIdx.x * blockDim.x + threadIdx.x;
    // u indexes h4 units: node = u>>6, pass = (u>>3)&7, c4 = u&7
    for (int u = i0; u < NN * HH / 4; u += gsz) {
        int node = u >> 6;
        int pass = (u >> 3) & 7;
        int c4 = u & 7;
        f4 v = *(const f4*)(W + (size_t)node * HH + pass * 32 + c4 * 4);
        h4 h;
        h[0] = (_Float16)v[0]; h[1] = (_Float16)v[1];
        h[2] = (_Float16)v[2]; h[3] = (_Float16)v[3];
        *(h4*)(Wcb + ((size_t)pass * NN + (size_t)node) * 32 + c4 * 4) = h;
    }
    for (int e = i0; e < EE; e += gsz) atomicAdd(&deg[ei[EE + e]], 1);
}

// ---------------- pack weights into MFMA-B fragment layout (fp16) ----------------
__global__ __launch_bounds__(256)
void k_pack(const float* __restrict__ W_node, const float* __restrict__ W_c1,
            const float* __restrict__ W_c2, const float* __restrict__ W_f1,
            const float* __restrict__ b_node, const float* __restrict__ b_c1,
            const float* __restrict__ b_c2, _Float16* __restrict__ pW,
            float* __restrict__ bB) {
    const int tid = threadIdx.x;
    if (blockIdx.x == 112) {  // combined phase-B bias: b_c1+b_c2+b_node@(I+W_c2)
        int c = tid;
        if (c < HH) {
            float a = 0.f;
            for (int k = 0; k < HH; ++k) a += b_node[k] * W_c2[k * HH + c];
            bB[c] = a + b_node[c] + b_c1[c] + b_c2[c];
        }
        return;
    }
    const int unit = blockIdx.x * 4 + (tid >> 6);
    const int lane = tid & 63, lm = lane & 15, lg = lane >> 4;
    const float* Ws;
    bool addI;
    int u = unit;
    if (u < 64)       { Ws = W_node; addI = false; }
    else if (u < 192) { Ws = W_c1;   addI = true;  u -= 64; }
    else if (u < 320) { Ws = W_c2;   addI = true;  u -= 192; }
    else              { Ws = W_f1;   addI = false; u -= 320; }
    const int kb = u >> 4, nb = u & 15;
    h8 hv;
#pragma unroll
    for (int j = 0; j < 8; ++j) {
        int kr = kb * 32 + lg * 8 + j;
        int col = nb * 16 + lm;
        float v = Ws[kr * HH + col];
        if (addI && kr == col) v += 1.f;
        hv[j] = (_Float16)v;
    }
    *(h8*)(pW + (size_t)unit * 512 + lane * 8) = hv;
}

// ---------------- two-level scan ----------------
__global__ __launch_bounds__(256)
void k_scan1(const int* __restrict__ deg, int* __restrict__ rowptr, int* __restrict__ bsums) {
    __shared__ int t[256];
    const int tid = threadIdx.x;
    int i = blockIdx.x * 256 + tid;
    int v = (i < NN) ? deg[i] : 0;
    t[tid] = v;
    __syncthreads();
#pragma unroll
    for (int off = 1; off < 256; off <<= 1) {
        int u = (tid >= off) ? t[tid - off] : 0;
        __syncthreads();
        t[tid] += u;
        __syncthreads();
    }
    if (i < NN) rowptr[i] = t[tid] - v;
    if (tid == 255) bsums[blockIdx.x] = t[tid];
}
__global__ __launch_bounds__(256)
void k_scan2(int* __restrict__ bsums) {
    __shared__ int t[256];
    const int tid = threadIdx.x;
    int v = (tid < 196) ? bsums[tid] : 0;
    t[tid] = v;
    __syncthreads();
#pragma unroll
    for (int off = 1; off < 256; off <<= 1) {
        int u = (tid >= off) ? t[tid - off] : 0;
        __syncthreads();
        t[tid] += u;
        __syncthreads();
    }
    if (tid < 196) bsums[tid] = t[tid] - v;
}
__global__ __launch_bounds__(256)
void k_scan3(int* __restrict__ rowptr, const int* __restrict__ bsums, int* __restrict__ pos) {
    int i = blockIdx.x * 256 + threadIdx.x;
    if (i < NN) {
        int r = rowptr[i] + bsums[blockIdx.x];
        rowptr[i] = r;
        pos[i] = r;
    }
    if (i == 0) rowptr[NN] = EE;
}

// ---------------- bin-scatter: packed (src:16 | fp16(w):16) 4B into CSR order ----------------
__global__ void k_ssort(const int* __restrict__ ei, const float* __restrict__ ew,
                        int* __restrict__ pos, unsigned int* __restrict__ esw) {
    int e = blockIdx.x * blockDim.x + threadIdx.x;
    if (e < EE) {
        int d = ei[EE + e];
        int p = atomicAdd(&pos[d], 1);
        _Float16 hw = (_Float16)ew[e];
        unsigned short hwb = *(unsigned short*)&hw;
        esw[p] = (unsigned int)ei[e] | ((unsigned int)hwb << 16);
    }
}

// ---------------- column-blocked gather: block -> (4 nodes, 1 pass); pass = blockIdx&7 ----------------
// Each XCD (via round-robin dispatch) sees one pass's 3.2 MB table -> L2-resident.
// Wave: 8 lanes per edge (cols cl*4..cl*4+4 of the 32-col block), 8 edges in flight.
__global__ __launch_bounds__(256)
void k_gatherCB(const int* __restrict__ rowptr, const unsigned int* __restrict__ esw,
                const _Float16* __restrict__ Wcb, const float* __restrict__ b_edge,
                _Float16* __restrict__ outHA) {
    const int wave = threadIdx.x >> 6;
    const int lane = threadIdx.x & 63;
    const int pass = blockIdx.x & 7;
    const int node = (blockIdx.x >> 3) * 4 + wave;
    if (node >= NN) return;
    const int eg = lane >> 3, cl = lane & 7;
    const _Float16* Wp = Wcb + (size_t)pass * NN * 32;
    int e = rowptr[node];
    const int end = rowptr[node + 1];
    f4 acc = {0.f, 0.f, 0.f, 0.f};
    // 16 edges per iteration: 2 independent gathers in flight per lane
    for (; e + 15 < end; e += 16) {
        unsigned int v0 = esw[e + eg];
        unsigned int v1 = esw[e + 8 + eg];
        h4 r0 = *(const h4*)(Wp + (size_t)(v0 & 0xFFFF) * 32 + cl * 4);
        h4 r1 = *(const h4*)(Wp + (size_t)(v1 & 0xFFFF) * 32 + cl * 4);
        unsigned short b0 = (unsigned short)(v0 >> 16);
        unsigned short b1 = (unsigned short)(v1 >> 16);
        float w0 = (float)*(_Float16*)&b0;
        float w1 = (float)*(_Float16*)&b1;
        f4 f0 = {(float)r0[0], (float)r0[1], (float)r0[2], (float)r0[3]};
        f4 f1 = {(float)r1[0], (float)r1[1], (float)r1[2], (float)r1[3]};
        acc += w0 * f0 + w1 * f1;
    }
    for (; e + 7 < end; e += 8) {
        unsigned int v = esw[e + eg];
        h4 r = *(const h4*)(Wp + (size_t)(v & 0xFFFF) * 32 + cl * 4);
        unsigned short b0 = (unsigned short)(v >> 16);
        float w = (float)*(_Float16*)&b0;
        f4 f = {(float)r[0], (float)r[1], (float)r[2], (float)r[3]};
        acc += w * f;
    }
    {
        int rem = end - e;
        if (eg < rem) {
            unsigned int v = esw[e + eg];
            h4 r = *(const h4*)(Wp + (size_t)(v & 0xFFFF) * 32 + cl * 4);
            unsigned short b0 = (unsigned short)(v >> 16);
            float w = (float)*(_Float16*)&b0;
            f4 f = {(float)r[0], (float)r[1], (float)r[2], (float)r[3]};
            acc += w * f;
        }
    }
    // reduce over edge groups (lane bits 3,4,5)
#pragma unroll
    for (int m = 8; m <= 32; m <<= 1) {
        acc[0] += __shfl_xor(acc[0], m);
        acc[1] += __shfl_xor(acc[1], m);
        acc[2] += __shfl_xor(acc[2], m);
        acc[3] += __shfl_xor(acc[3], m);
    }
    if (eg == 0) {
        f4 b = *(const f4*)(b_edge + pass * 32 + cl * 4);
        acc += b;
        h4 hv;
        hv[0] = (_Float16)acc[0]; hv[1] = (_Float16)acc[1];
        hv[2] = (_Float16)acc[2]; hv[3] = (_Float16)acc[3];
        *(h4*)(outHA + (size_t)node * HH + pass * 32 + cl * 4) = hv;
    }
}

// ---------------- weight-stationary streaming GEMM (R7-proven) ----------------
// MODE: 0 = plain store, 1 = relu(acc+bias) + BN stats.
template <int KB, int MODE>
__global__ __launch_bounds__(256, 2)
void k_gemm(const _Float16* __restrict__ A16, const _Float16* __restrict__ pWph,
            const float* __restrict__ bias, _Float16* __restrict__ C,
            float* __restrict__ stats) {
    constexpr int K = KB * 32;
    constexpr int RB = K * 2;
    constexpr int KW = KB * 4;
    constexpr int U = (32 * KW) / 256;
    __shared__ __align__(16) char sA[32 * RB];
    const int tid = threadIdx.x;
    const int w = tid >> 6, l = tid & 63;
    const int lm = l & 15, lg = l >> 4;

    h8 wreg[KB][4];
#pragma unroll
    for (int kb = 0; kb < KB; ++kb)
#pragma unroll
        for (int n = 0; n < 4; ++n)
            wreg[kb][n] = *(const h8*)(pWph + (size_t)(kb * 16 + w * 4 + n) * 512 + l * 8);

    float breg[4];
    if constexpr (MODE == 1) {
#pragma unroll
        for (int n = 0; n < 4; ++n) breg[n] = bias[w * 64 + n * 16 + lm];
    }
    float sS[4] = {0.f, 0.f, 0.f, 0.f}, sQ[4] = {0.f, 0.f, 0.f, 0.f};

    const int NT = (NN + 31) / 32;
    int4 pre[U];
    int t = blockIdx.x;
#pragma unroll
    for (int j = 0; j < U; ++j) {
        int unit = tid * U + j;
        int r = unit / KW, s = unit % KW;
        int grow = t * 32 + r;
        int4 z = {0, 0, 0, 0};
        pre[j] = (grow < NN) ? *(const int4*)(A16 + (size_t)grow * K + s * 8) : z;
    }

    for (; t < NT; t += gridDim.x) {
        __syncthreads();
#pragma unroll
        for (int j = 0; j < U; ++j) {
            int unit = tid * U + j;
            int r = unit / KW, s = unit % KW;
            *(int4*)(sA + r * RB + SWZ(r, s * 16)) = pre[j];
        }
        int tn = t + gridDim.x;
        if (tn < NT) {
#pragma unroll
            for (int j = 0; j < U; ++j) {
                int unit = tid * U + j;
                int r = unit / KW, s = unit % KW;
                int grow = tn * 32 + r;
                int4 z = {0, 0, 0, 0};
                pre[j] = (grow < NN) ? *(const int4*)(A16 + (size_t)grow * K + s * 8) : z;
            }
        }
        __syncthreads();

        f4 acc[2][4];
        const f4 z4 = {0.f, 0.f, 0.f, 0.f};
#pragma unroll
        for (int rf = 0; rf < 2; ++rf)
#pragma unroll
            for (int n = 0; n < 4; ++n) acc[rf][n] = z4;

#pragma unroll
        for (int kb = 0; kb < KB; ++kb) {
            h8 a0 = *(const h8*)(sA + lm * RB + SWZ(lm, kb * 64 + lg * 16));
            h8 a1 = *(const h8*)(sA + (16 + lm) * RB + SWZ(16 + lm, kb * 64 + lg * 16));
#pragma unroll
            for (int n = 0; n < 4; ++n) {
                acc[0][n] = __builtin_amdgcn_mfma_f32_16x16x32_f16(a0, wreg[kb][n], acc[0][n], 0, 0, 0);
                acc[1][n] = __builtin_amdgcn_mfma_f32_16x16x32_f16(a1, wreg[kb][n], acc[1][n], 0, 0, 0);
            }
        }

        const int row0 = t * 32;
#pragma unroll
        for (int rf = 0; rf < 2; ++rf)
#pragma unroll
            for (int n = 0; n < 4; ++n) {
                const int col = w * 64 + n * 16 + lm;
#pragma unroll
                for (int q = 0; q < 4; ++q) {
                    int grow = row0 + rf * 16 + lg * 4 + q;
                    if (grow < NN) {
                        float v = acc[rf][n][q];
                        if constexpr (MODE == 1) {
                            v = fmaxf(v + breg[n], 0.f);
                            sS[n] += v;
                            sQ[n] += v * v;
                        }
                        C[(size_t)grow * HH + col] = (_Float16)v;
                    }
                }
            }
    }

    if constexpr (MODE == 1) {
#pragma unroll
        for (int n = 0; n < 4; ++n) {
            float s = sS[n];
            s += __shfl_xor(s, 16); s += __shfl_xor(s, 32);
            float q = sQ[n];
            q += __shfl_xor(q, 16); q += __shfl_xor(q, 32);
            if (lg == 0) {
                atomicAdd(&stats[w * 64 + n * 16 + lm], s);
                atomicAdd(&stats[HH + w * 64 + n * 16 + lm], q);
            }
        }
    }
}

// ---------------- fused phase A+B: outB = relu(h_a@(I+Wc1) + (x@Wn)@(I+Wc2) + bB) ----------------
__global__ __launch_bounds__(512, 1)
void k_gemmB2(const float* __restrict__ x, const _Float16* __restrict__ A1,
              const _Float16* __restrict__ pW, const float* __restrict__ bB,
              _Float16* __restrict__ C) {
    __shared__ __align__(16) char sm[40960];
    const int tid = threadIdx.x;
    const int w = tid >> 6, l = tid & 63;
    const int lm = l & 15, lg = l >> 4;
    const int rx = tid >> 4, sx = tid & 15;

    h8 w1[8][2], w2[8][2], wn[4][2];
#pragma unroll
    for (int kb = 0; kb < 8; ++kb)
#pragma unroll
        for (int n = 0; n < 2; ++n) {
            w1[kb][n] = *(const h8*)(pW + OFF_C1 + (size_t)(kb * 16 + w * 2 + n) * 512 + l * 8);
            w2[kb][n] = *(const h8*)(pW + OFF_C2 + (size_t)(kb * 16 + w * 2 + n) * 512 + l * 8);
        }
#pragma unroll
    for (int kb = 0; kb < 4; ++kb)
#pragma unroll
        for (int n = 0; n < 2; ++n)
            wn[kb][n] = *(const h8*)(pW + OFF_NODE + (size_t)(kb * 16 + w * 2 + n) * 512 + l * 8);

    float breg[2];
#pragma unroll
    for (int n = 0; n < 2; ++n) breg[n] = bB[w * 32 + n * 16 + lm];

    const int NT = (NN + 31) / 32;
    f4 pXa, pXb;
    int4 p1[2];
    int t = blockIdx.x;
    {
        int grow = t * 32 + rx;
        const f4 zf = {0.f, 0.f, 0.f, 0.f};
        pXa = (grow < NN) ? *(const f4*)(x + (size_t)grow * FF + sx * 8) : zf;
        pXb = (grow < NN) ? *(const f4*)(x + (size_t)grow * FF + sx * 8 + 4) : zf;
#pragma unroll
        for (int j = 0; j < 2; ++j) {
            int unit = tid * 2 + j;
            int r = unit >> 5, s = unit & 31;
            int g2 = t * 32 + r;
            int4 z = {0, 0, 0, 0};
            p1[j] = (g2 < NN) ? *(const int4*)(A1 + (size_t)g2 * HH + s * 8) : z;
        }
    }

    for (; t < NT; t += gridDim.x) {
        __syncthreads();  // b0
        {
            h8 hx;
            hx[0] = (_Float16)pXa[0]; hx[1] = (_Float16)pXa[1];
            hx[2] = (_Float16)pXa[2]; hx[3] = (_Float16)pXa[3];
            hx[4] = (_Float16)pXb[0]; hx[5] = (_Float16)pXb[1];
            hx[6] = (_Float16)pXb[2]; hx[7] = (_Float16)pXb[3];
            *(int4*)(sm + rx * 256 + SWZ(rx, sx * 16)) = *(int4*)&hx;
        }
#pragma unroll
        for (int j = 0; j < 2; ++j) {
            int unit = tid * 2 + j;
            int r = unit >> 5, s = unit & 31;
            *(int4*)(sm + 8192 + r * 512 + SWZ(r, s * 16)) = p1[j];
        }
        int tn = t + gridDim.x;
        if (tn < NT) {
            int grow = tn * 32 + rx;
            const f4 zf = {0.f, 0.f, 0.f, 0.f};
            pXa = (grow < NN) ? *(const f4*)(x + (size_t)grow * FF + sx * 8) : zf;
            pXb = (grow < NN) ? *(const f4*)(x + (size_t)grow * FF + sx * 8 + 4) : zf;
#pragma unroll
            for (int j = 0; j < 2; ++j) {
                int unit = tid * 2 + j;
                int r = unit >> 5, s = unit & 31;
                int g2 = tn * 32 + r;
                int4 z = {0, 0, 0, 0};
                p1[j] = (g2 < NN) ? *(const int4*)(A1 + (size_t)g2 * HH + s * 8) : z;
            }
        }
        __syncthreads();  // b1

        // hx0 = x @ W_node -> sHX
        {
            f4 acch[2][2];
            const f4 z4 = {0.f, 0.f, 0.f, 0.f};
#pragma unroll
            for (int rf = 0; rf < 2; ++rf)
#pragma unroll
                for (int n = 0; n < 2; ++n) acch[rf][n] = z4;
#pragma unroll
            for (int kb = 0; kb < 4; ++kb) {
                h8 a0 = *(const h8*)(sm + lm * 256 + SWZ(lm, kb * 64 + lg * 16));
                h8 a1 = *(const h8*)(sm + (16 + lm) * 256 + SWZ(16 + lm, kb * 64 + lg * 16));
#pragma unroll
                for (int n = 0; n < 2; ++n) {
                    acch[0][n] = __builtin_amdgcn_mfma_f32_16x16x32_f16(a0, wn[kb][n], acch[0][n], 0, 0, 0);
                    acch[1][n] = __builtin_amdgcn_mfma_f32_16x16x32_f16(a1, wn[kb][n], acch[1][n], 0, 0, 0);
                }
            }
#pragma unroll
            for (int rf = 0; rf < 2; ++rf)
#pragma unroll
                for (int n = 0; n < 2; ++n) {
                    int c2 = (w * 32 + n * 16 + lm) * 2;
#pragma unroll
                    for (int q = 0; q < 4; ++q) {
                        int r = rf * 16 + lg * 4 + q;
                        *(_Float16*)(sm + 24576 + r * 512 + SWZ(r, c2)) = (_Float16)acch[rf][n][q];
                    }
                }
        }
        __syncthreads();  // b2

        f4 acc[2][2];
        const f4 z4 = {0.f, 0.f, 0.f, 0.f};
#pragma unroll
        for (int rf = 0; rf < 2; ++rf)
#pragma unroll
            for (int n = 0; n < 2; ++n) acc[rf][n] = z4;

#pragma unroll
        for (int kb = 0; kb < 8; ++kb) {
            h8 a10 = *(const h8*)(sm + 8192 + lm * 512 + SWZ(lm, kb * 64 + lg * 16));
            h8 a11 = *(const h8*)(sm + 8192 + (16 + lm) * 512 + SWZ(16 + lm, kb * 64 + lg * 16));
            h8 a20 = *(const h8*)(sm + 24576 + lm * 512 + SWZ(lm, kb * 64 + lg * 16));
            h8 a21 = *(const h8*)(sm + 24576 + (16 + lm) * 512 + SWZ(16 + lm, kb * 64 + lg * 16));
#pragma unroll
            for (int n = 0; n < 2; ++n) {
                acc[0][n] = __builtin_amdgcn_mfma_f32_16x16x32_f16(a10, w1[kb][n], acc[0][n], 0, 0, 0);
                acc[1][n] = __builtin_amdgcn_mfma_f32_16x16x32_f16(a11, w1[kb][n], acc[1][n], 0, 0, 0);
                acc[0][n] = __builtin_amdgcn_mfma_f32_16x16x32_f16(a20, w2[kb][n], acc[0][n], 0, 0, 0);
                acc[1][n] = __builtin_amdgcn_mfma_f32_16x16x32_f16(a21, w2[kb][n], acc[1][n], 0, 0, 0);
            }
        }

        const int row0 = t * 32;
#pragma unroll
        for (int rf = 0; rf < 2; ++rf)
#pragma unroll
            for (int n = 0; n < 2; ++n) {
                const int col = w * 32 + n * 16 + lm;
#pragma unroll
                for (int q = 0; q < 4; ++q) {
                    int grow = row0 + rf * 16 + lg * 4 + q;
                    if (grow < NN) {
                        float v = fmaxf(acc[rf][n][q] + breg[n], 0.f);
                        C[(size_t)grow * HH + col] = (_Float16)v;
                    }
                }
            }
    }
}

// ---------------- BN fold + pack final weights into MFMA-B fragments ----------------
__global__ __launch_bounds__(256)
void k_bnprep(const float* __restrict__ stats, const float* __restrict__ gamma,
              const float* __restrict__ beta, const float* __restrict__ W_f2,
              const float* __restrict__ b_f2, _Float16* __restrict__ pWf,
              float* __restrict__ bfold) {
    __shared__ float sh[HH];
    __shared__ float ssc[HH];
    const int tid = threadIdx.x;
    const float invN = 1.0f / (float)NN;
    {
        float mu = stats[tid] * invN;
        float var = stats[HH + tid] * invN - mu * mu;
        float scale = gamma[tid] * rsqrtf(var + BN_EPS);
        sh[tid] = beta[tid] - mu * scale;
        ssc[tid] = scale;
    }
    __syncthreads();
    if (tid < CC) {
        float b = b_f2[tid];
        for (int k = 0; k < HH; ++k) b += sh[k] * W_f2[k * CC + tid];
        bfold[tid] = b;
    }
    const int w = tid >> 6, l = tid & 63;
    const int lm = l & 15, lg = l >> 4;
#pragma unroll
    for (int i = 0; i < 6; ++i) {
        int u = w + i * 4;  // 0..23
        int kb = u / 3, nb = u % 3;
        h8 hv;
#pragma unroll
        for (int j = 0; j < 8; ++j) {
            int k = kb * 32 + lg * 8 + j;
            int c = nb * 16 + lm;
            float v = (c < CC) ? ssc[k] * W_f2[k * CC + c] : 0.f;
            hv[j] = (_Float16)v;
        }
        *(h8*)(pWf + (size_t)u * 512 + l * 8) = hv;
    }
}

// ---------------- final via MFMA: out = h @ (scale*W_f2) + bfold ----------------
__global__ __launch_bounds__(256)
void k_finalM(const _Float16* __restrict__ h, const _Float16* __restrict__ pWf,
              const float* __restrict__ bfold, float* __restrict__ out) {
    __shared__ __align__(16) char sA[64 * 512];
    const int tid = threadIdx.x;
    const int w = tid >> 6, l = tid & 63;
    const int lm = l & 15, lg = l >> 4;

    h8 wreg[8][3];
#pragma unroll
    for (int kb = 0; kb < 8; ++kb)
#pragma unroll
        for (int nb = 0; nb < 3; ++nb)
            wreg[kb][nb] = *(const h8*)(pWf + (size_t)(kb * 3 + nb) * 512 + l * 8);

    const int row0 = blockIdx.x * 64;
#pragma unroll
    for (int j = 0; j < 8; ++j) {
        int unit = tid * 8 + j;
        int r = unit >> 5, s = unit & 31;
        int grow = row0 + r;
        int4 z = {0, 0, 0, 0};
        int4 v = (grow < NN) ? *(const int4*)(h + (size_t)grow * HH + s * 8) : z;
        *(int4*)(sA + r * 512 + SWZ(r, s * 16)) = v;
    }
    __syncthreads();

    f4 acc[3];
    const f4 z4 = {0.f, 0.f, 0.f, 0.f};
#pragma unroll
    for (int nb = 0; nb < 3; ++nb) acc[nb] = z4;

    const int ar = w * 16 + lm;
#pragma unroll
    for (int kb = 0; kb < 8; ++kb) {
        h8 a = *(const h8*)(sA + ar * 512 + SWZ(ar, kb * 64 + lg * 16));
#pragma unroll
        for (int nb = 0; nb < 3; ++nb)
            acc[nb] = __builtin_amdgcn_mfma_f32_16x16x32_f16(a, wreg[kb][nb], acc[nb], 0, 0, 0);
    }

#pragma unroll
    for (int nb = 0; nb < 3; ++nb) {
        int col = nb * 16 + lm;
        if (col < CC) {
            float bb = bfold[col];
#pragma unroll
            for (int q = 0; q < 4; ++q) {
                int grow = row0 + w * 16 + lg * 4 + q;
                if (grow < NN) out[(size_t)grow * CC + col] = acc[nb][q] + bb;
            }
        }
    }
}

extern "C" void kernel_launch(void* const* d_in, const int* in_sizes, int n_in,
                              void* d_out, int out_size, void* d_ws, size_t ws_size,
                              hipStream_t stream) {
    const float* x      = (const float*)d_in[0];
    const int*   ei     = (const int*)d_in[1];
    const float* ew     = (const float*)d_in[2];
    const float* W_edge = (const float*)d_in[3];
    const float* b_edge = (const float*)d_in[4];
    const float* W_node = (const float*)d_in[5];
    const float* b_node = (const float*)d_in[6];
    const float* W_c1   = (const float*)d_in[7];
    const float* b_c1   = (const float*)d_in[8];
    const float* W_c2   = (const float*)d_in[9];
    const float* b_c2   = (const float*)d_in[10];
    const float* W_f1   = (const float*)d_in[11];
    const float* b_f1   = (const float*)d_in[12];
    const float* gamma  = (const float*)d_in[13];
    const float* beta   = (const float*)d_in[14];
    const float* W_f2   = (const float*)d_in[15];
    const float* b_f2   = (const float*)d_in[16];
    float* out = (float*)d_out;

    const size_t NNH = (size_t)NN * HH;
    _Float16* bufA = (_Float16*)d_ws;            // h_a -> outB (in place)
    _Float16* bufH = bufA + NNH;                 // h
    _Float16* Wcb  = bufH + NNH;                 // fp16 W_edge, column-blocked [8][NN][32]
    unsigned int* esw = (unsigned int*)(Wcb + NNH);  // E packed
    float* stats   = (float*)(esw + EE);         // 512
    float* bB      = stats + 2 * HH;             // 256
    float* bfold   = bB + HH;                    // 64
    _Float16* pWf  = (_Float16*)(bfold + 64);    // 24*512
    _Float16* pW   = pWf + 24 * 512;             // PW_HALVES
    int* deg       = (int*)(pW + PW_HALVES);     // N
    int* rowptr    = deg + NN;                   // N+1
    int* pos       = rowptr + NN + 1;            // N
    int* bsums     = pos + NN;                   // 256

    k_init<<<196, 256, 0, stream>>>(stats, deg);
    k_prep<<<2048, 256, 0, stream>>>(W_edge, Wcb, ei, deg);
    k_pack<<<113, 256, 0, stream>>>(W_node, W_c1, W_c2, W_f1, b_node, b_c1, b_c2, pW, bB);
    k_scan1<<<196, 256, 0, stream>>>(deg, rowptr, bsums);
    k_scan2<<<1, 256, 0, stream>>>(bsums);
    k_scan3<<<196, 256, 0, stream>>>(rowptr, bsums, pos);
    k_ssort<<<(EE + 255) / 256, 256, 0, stream>>>(ei, ew, pos, esw);
    k_gatherCB<<<12500 * 8, 256, 0, stream>>>(rowptr, esw, Wcb, b_edge, bufA);

    // GB2: outB = relu(h_a@(I+Wc1) + (x@Wn)@(I+Wc2) + bB) -> bufA (in place)
    k_gemmB2<<<256, 512, 0, stream>>>(x, bufA, pW, bB, bufA);
    // GC: h = relu(outB @ W_f1 + b_f1) + BN stats -> bufH
    k_gemm<8, 1><<<512, 256, 0, stream>>>(bufA, pW + OFF_F1, b_f1, bufH, stats);

    k_bnprep<<<1, 256, 0, stream>>>(stats, gamma, beta, W_f2, b_f2, pWf, bfold);
    k_finalM<<<(NN + 63) / 64, 256, 0, stream>>>(bufH, pWf, bfold, out);
}

// Round 10
// 268.137 us; speedup vs baseline: 1.2328x; 1.2328x over previous
//
#include <hip/hip_runtime.h>

#define NN 50000
#define EE 800000
#define FF 128
#define HH 256
#define CC 40
#define BN_EPS 1e-5f

typedef float f4 __attribute__((ext_vector_type(4)));
typedef _Float16 h8 __attribute__((ext_vector_type(8)));
typedef _Float16 h4 __attribute__((ext_vector_type(4)));

#define OFF_NODE 0            // 4*16 units
#define OFF_C1   32768        // 8*16 units
#define OFF_C2   98304
#define OFF_F1   163840
#define PW_HALVES 229376

#define SWZ(row, c2) ((c2) ^ (((row) & 7) << 4))

// ---------------- prep: W_edge -> fp16  +  histogram of dst ----------------
__global__ __launch_bounds__(256)
void k_prep(const float* __restrict__ W, _Float16* __restrict__ W16,
            const int* __restrict__ ei, int* __restrict__ deg) {
    const int gsz = gridDim.x * blockDim.x;
    const int i0 = blockIdx.x * blockDim.x + threadIdx.x;
    for (int j = i0; j < NN * HH / 8; j += gsz) {
        f4 v0 = ((const f4*)W)[j * 2];
        f4 v1 = ((const f4*)W)[j * 2 + 1];
        h8 h;
        h[0] = (_Float16)v0[0]; h[1] = (_Float16)v0[1];
        h[2] = (_Float16)v0[2]; h[3] = (_Float16)v0[3];
        h[4] = (_Float16)v1[0]; h[5] = (_Float16)v1[1];
        h[6] = (_Float16)v1[2]; h[7] = (_Float16)v1[3];
        ((h8*)W16)[j] = h;
    }
    for (int e = i0; e < EE; e += gsz) atomicAdd(&deg[ei[EE + e]], 1);
}

// ---------------- pack weights into MFMA-B fragment layout (fp16) ----------------
__global__ __launch_bounds__(256)
void k_pack(const float* __restrict__ W_node, const float* __restrict__ W_c1,
            const float* __restrict__ W_c2, const float* __restrict__ W_f1,
            const float* __restrict__ b_node, const float* __restrict__ b_c1,
            const float* __restrict__ b_c2, _Float16* __restrict__ pW,
            float* __restrict__ bB) {
    const int tid = threadIdx.x;
    if (blockIdx.x == 112) {  // combined phase-B bias: b_c1+b_c2+b_node@(I+W_c2)
        int c = tid;
        if (c < HH) {
            float a = 0.f;
            for (int k = 0; k < HH; ++k) a += b_node[k] * W_c2[k * HH + c];
            bB[c] = a + b_node[c] + b_c1[c] + b_c2[c];
        }
        return;
    }
    const int unit = blockIdx.x * 4 + (tid >> 6);
    const int lane = tid & 63, lm = lane & 15, lg = lane >> 4;
    const float* Ws;
    bool addI;
    int u = unit;
    if (u < 64)       { Ws = W_node; addI = false; }
    else if (u < 192) { Ws = W_c1;   addI = true;  u -= 64; }
    else if (u < 320) { Ws = W_c2;   addI = true;  u -= 192; }
    else              { Ws = W_f1;   addI = false; u -= 320; }
    const int kb = u >> 4, nb = u & 15;
    h8 hv;
#pragma unroll
    for (int j = 0; j < 8; ++j) {
        int kr = kb * 32 + lg * 8 + j;
        int col = nb * 16 + lm;
        float v = Ws[kr * HH + col];
        if (addI && kr == col) v += 1.f;
        hv[j] = (_Float16)v;
    }
    *(h8*)(pW + (size_t)unit * 512 + lane * 8) = hv;
}

// ---------------- two-level scan ----------------
__global__ __launch_bounds__(256)
void k_scan1(const int* __restrict__ deg, int* __restrict__ rowptr, int* __restrict__ bsums) {
    __shared__ int t[256];
    const int tid = threadIdx.x;
    int i = blockIdx.x * 256 + tid;
    int v = (i < NN) ? deg[i] : 0;
    t[tid] = v;
    __syncthreads();
#pragma unroll
    for (int off = 1; off < 256; off <<= 1) {
        int u = (tid >= off) ? t[tid - off] : 0;
        __syncthreads();
        t[tid] += u;
        __syncthreads();
    }
    if (i < NN) rowptr[i] = t[tid] - v;
    if (tid == 255) bsums[blockIdx.x] = t[tid];
}
__global__ __launch_bounds__(256)
void k_scan2(int* __restrict__ bsums) {
    __shared__ int t[256];
    const int tid = threadIdx.x;
    int v = (tid < 196) ? bsums[tid] : 0;
    t[tid] = v;
    __syncthreads();
#pragma unroll
    for (int off = 1; off < 256; off <<= 1) {
        int u = (tid >= off) ? t[tid - off] : 0;
        __syncthreads();
        t[tid] += u;
        __syncthreads();
    }
    if (tid < 196) bsums[tid] = t[tid] - v;
}
__global__ __launch_bounds__(256)
void k_scan3(int* __restrict__ rowptr, const int* __restrict__ bsums, int* __restrict__ pos) {
    int i = blockIdx.x * 256 + threadIdx.x;
    if (i < NN) {
        int r = rowptr[i] + bsums[blockIdx.x];
        rowptr[i] = r;
        pos[i] = r;
    }
    if (i == 0) rowptr[NN] = EE;
}

// ---------------- bin-scatter: packed (src:16 | fp16(w):16) 4B into CSR order ----------------
__global__ void k_ssort(const int* __restrict__ ei, const float* __restrict__ ew,
                        int* __restrict__ pos, unsigned int* __restrict__ esw) {
    int e = blockIdx.x * blockDim.x + threadIdx.x;
    if (e < EE) {
        int d = ei[EE + e];
        int p = atomicAdd(&pos[d], 1);
        _Float16 hw = (_Float16)ew[e];
        unsigned short hwb = *(unsigned short*)&hw;
        esw[p] = (unsigned int)ei[e] | ((unsigned int)hwb << 16);
    }
}

// ---------------- gather-accumulate: one wave per node, unroll 8 ----------------
__global__ __launch_bounds__(256)
void k_gather(const int* __restrict__ rowptr, const unsigned int* __restrict__ esw,
              const _Float16* __restrict__ W16, const float* __restrict__ b_edge,
              _Float16* __restrict__ outHA) {
    const int wave = threadIdx.x >> 6;
    const int lane = threadIdx.x & 63;
    const int node = blockIdx.x * 4 + wave;
    if (node >= NN) return;
    int e = rowptr[node];
    const int end = rowptr[node + 1];
    const int c0 = lane * 4;
    f4 acc0 = {0.f, 0.f, 0.f, 0.f}, acc1 = {0.f, 0.f, 0.f, 0.f};
    for (; e + 7 < end; e += 8) {
        unsigned int v[8];
        h4 r[8];
#pragma unroll
        for (int j = 0; j < 8; ++j) v[j] = esw[e + j];
#pragma unroll
        for (int j = 0; j < 8; ++j)
            r[j] = *(const h4*)(W16 + (size_t)(v[j] & 0xFFFF) * HH + c0);
#pragma unroll
        for (int j = 0; j < 8; j += 2) {
            unsigned short b0 = (unsigned short)(v[j] >> 16);
            unsigned short b1 = (unsigned short)(v[j + 1] >> 16);
            float w0 = (float)*(_Float16*)&b0;
            float w1 = (float)*(_Float16*)&b1;
            f4 f0 = {(float)r[j][0], (float)r[j][1], (float)r[j][2], (float)r[j][3]};
            f4 f1 = {(float)r[j + 1][0], (float)r[j + 1][1], (float)r[j + 1][2], (float)r[j + 1][3]};
            acc0 += w0 * f0;
            acc1 += w1 * f1;
        }
    }
    for (; e < end; ++e) {
        unsigned int v = esw[e];
        unsigned short bb = (unsigned short)(v >> 16);
        h4 rr = *(const h4*)(W16 + (size_t)(v & 0xFFFF) * HH + c0);
        f4 ff = {(float)rr[0], (float)rr[1], (float)rr[2], (float)rr[3]};
        acc0 += (float)*(_Float16*)&bb * ff;
    }
    f4 b = *(const f4*)(b_edge + c0);
    f4 acc = acc0 + acc1 + b;
    h4 hv;
    hv[0] = (_Float16)acc[0]; hv[1] = (_Float16)acc[1];
    hv[2] = (_Float16)acc[2]; hv[3] = (_Float16)acc[3];
    *(h4*)(outHA + (size_t)node * HH + c0) = hv;
}

// ---------------- weight-stationary streaming GEMM (R7-proven) ----------------
// MODE: 0 = plain store, 1 = relu(acc+bias) + BN stats.
template <int KB, int MODE>
__global__ __launch_bounds__(256, 2)
void k_gemm(const _Float16* __restrict__ A16, const _Float16* __restrict__ pWph,
            const float* __restrict__ bias, _Float16* __restrict__ C,
            float* __restrict__ stats) {
    constexpr int K = KB * 32;
    constexpr int RB = K * 2;
    constexpr int KW = KB * 4;
    constexpr int U = (32 * KW) / 256;
    __shared__ __align__(16) char sA[32 * RB];
    const int tid = threadIdx.x;
    const int w = tid >> 6, l = tid & 63;
    const int lm = l & 15, lg = l >> 4;

    h8 wreg[KB][4];
#pragma unroll
    for (int kb = 0; kb < KB; ++kb)
#pragma unroll
        for (int n = 0; n < 4; ++n)
            wreg[kb][n] = *(const h8*)(pWph + (size_t)(kb * 16 + w * 4 + n) * 512 + l * 8);

    float breg[4];
    if constexpr (MODE == 1) {
#pragma unroll
        for (int n = 0; n < 4; ++n) breg[n] = bias[w * 64 + n * 16 + lm];
    }
    float sS[4] = {0.f, 0.f, 0.f, 0.f}, sQ[4] = {0.f, 0.f, 0.f, 0.f};

    const int NT = (NN + 31) / 32;
    int4 pre[U];
    int t = blockIdx.x;
#pragma unroll
    for (int j = 0; j < U; ++j) {
        int unit = tid * U + j;
        int r = unit / KW, s = unit % KW;
        int grow = t * 32 + r;
        int4 z = {0, 0, 0, 0};
        pre[j] = (grow < NN) ? *(const int4*)(A16 + (size_t)grow * K + s * 8) : z;
    }

    for (; t < NT; t += gridDim.x) {
        __syncthreads();
#pragma unroll
        for (int j = 0; j < U; ++j) {
            int unit = tid * U + j;
            int r = unit / KW, s = unit % KW;
            *(int4*)(sA + r * RB + SWZ(r, s * 16)) = pre[j];
        }
        int tn = t + gridDim.x;
        if (tn < NT) {
#pragma unroll
            for (int j = 0; j < U; ++j) {
                int unit = tid * U + j;
                int r = unit / KW, s = unit % KW;
                int grow = tn * 32 + r;
                int4 z = {0, 0, 0, 0};
                pre[j] = (grow < NN) ? *(const int4*)(A16 + (size_t)grow * K + s * 8) : z;
            }
        }
        __syncthreads();

        f4 acc[2][4];
        const f4 z4 = {0.f, 0.f, 0.f, 0.f};
#pragma unroll
        for (int rf = 0; rf < 2; ++rf)
#pragma unroll
            for (int n = 0; n < 4; ++n) acc[rf][n] = z4;

#pragma unroll
        for (int kb = 0; kb < KB; ++kb) {
            h8 a0 = *(const h8*)(sA + lm * RB + SWZ(lm, kb * 64 + lg * 16));
            h8 a1 = *(const h8*)(sA + (16 + lm) * RB + SWZ(16 + lm, kb * 64 + lg * 16));
#pragma unroll
            for (int n = 0; n < 4; ++n) {
                acc[0][n] = __builtin_amdgcn_mfma_f32_16x16x32_f16(a0, wreg[kb][n], acc[0][n], 0, 0, 0);
                acc[1][n] = __builtin_amdgcn_mfma_f32_16x16x32_f16(a1, wreg[kb][n], acc[1][n], 0, 0, 0);
            }
        }

        const int row0 = t * 32;
#pragma unroll
        for (int rf = 0; rf < 2; ++rf)
#pragma unroll
            for (int n = 0; n < 4; ++n) {
                const int col = w * 64 + n * 16 + lm;
#pragma unroll
                for (int q = 0; q < 4; ++q) {
                    int grow = row0 + rf * 16 + lg * 4 + q;
                    if (grow < NN) {
                        float v = acc[rf][n][q];
                        if constexpr (MODE == 1) {
                            v = fmaxf(v + breg[n], 0.f);
                            sS[n] += v;
                            sQ[n] += v * v;
                        }
                        C[(size_t)grow * HH + col] = (_Float16)v;
                    }
                }
            }
    }

    if constexpr (MODE == 1) {
#pragma unroll
        for (int n = 0; n < 4; ++n) {
            float s = sS[n];
            s += __shfl_xor(s, 16); s += __shfl_xor(s, 32);
            float q = sQ[n];
            q += __shfl_xor(q, 16); q += __shfl_xor(q, 32);
            if (lg == 0) {
                atomicAdd(&stats[w * 64 + n * 16 + lm], s);
                atomicAdd(&stats[HH + w * 64 + n * 16 + lm], q);
            }
        }
    }
}

// ---------------- fused phase A+B: outB = relu(h_a@(I+Wc1) + (x@Wn)@(I+Wc2) + bB) ----------------
__global__ __launch_bounds__(512, 1)
void k_gemmB2(const float* __restrict__ x, const _Float16* __restrict__ A1,
              const _Float16* __restrict__ pW, const float* __restrict__ bB,
              _Float16* __restrict__ C) {
    __shared__ __align__(16) char sm[40960];
    const int tid = threadIdx.x;
    const int w = tid >> 6, l = tid & 63;
    const int lm = l & 15, lg = l >> 4;
    const int rx = tid >> 4, sx = tid & 15;

    h8 w1[8][2], w2[8][2], wn[4][2];
#pragma unroll
    for (int kb = 0; kb < 8; ++kb)
#pragma unroll
        for (int n = 0; n < 2; ++n) {
            w1[kb][n] = *(const h8*)(pW + OFF_C1 + (size_t)(kb * 16 + w * 2 + n) * 512 + l * 8);
            w2[kb][n] = *(const h8*)(pW + OFF_C2 + (size_t)(kb * 16 + w * 2 + n) * 512 + l * 8);
        }
#pragma unroll
    for (int kb = 0; kb < 4; ++kb)
#pragma unroll
        for (int n = 0; n < 2; ++n)
            wn[kb][n] = *(const h8*)(pW + OFF_NODE + (size_t)(kb * 16 + w * 2 + n) * 512 + l * 8);

    float breg[2];
#pragma unroll
    for (int n = 0; n < 2; ++n) breg[n] = bB[w * 32 + n * 16 + lm];

    const int NT = (NN + 31) / 32;
    f4 pXa, pXb;
    int4 p1[2];
    int t = blockIdx.x;
    {
        int grow = t * 32 + rx;
        const f4 zf = {0.f, 0.f, 0.f, 0.f};
        pXa = (grow < NN) ? *(const f4*)(x + (size_t)grow * FF + sx * 8) : zf;
        pXb = (grow < NN) ? *(const f4*)(x + (size_t)grow * FF + sx * 8 + 4) : zf;
#pragma unroll
        for (int j = 0; j < 2; ++j) {
            int unit = tid * 2 + j;
            int r = unit >> 5, s = unit & 31;
            int g2 = t * 32 + r;
            int4 z = {0, 0, 0, 0};
            p1[j] = (g2 < NN) ? *(const int4*)(A1 + (size_t)g2 * HH + s * 8) : z;
        }
    }

    for (; t < NT; t += gridDim.x) {
        __syncthreads();  // b0
        {
            h8 hx;
            hx[0] = (_Float16)pXa[0]; hx[1] = (_Float16)pXa[1];
            hx[2] = (_Float16)pXa[2]; hx[3] = (_Float16)pXa[3];
            hx[4] = (_Float16)pXb[0]; hx[5] = (_Float16)pXb[1];
            hx[6] = (_Float16)pXb[2]; hx[7] = (_Float16)pXb[3];
            *(int4*)(sm + rx * 256 + SWZ(rx, sx * 16)) = *(int4*)&hx;
        }
#pragma unroll
        for (int j = 0; j < 2; ++j) {
            int unit = tid * 2 + j;
            int r = unit >> 5, s = unit & 31;
            *(int4*)(sm + 8192 + r * 512 + SWZ(r, s * 16)) = p1[j];
        }
        int tn = t + gridDim.x;
        if (tn < NT) {
            int grow = tn * 32 + rx;
            const f4 zf = {0.f, 0.f, 0.f, 0.f};
            pXa = (grow < NN) ? *(const f4*)(x + (size_t)grow * FF + sx * 8) : zf;
            pXb = (grow < NN) ? *(const f4*)(x + (size_t)grow * FF + sx * 8 + 4) : zf;
#pragma unroll
            for (int j = 0; j < 2; ++j) {
                int unit = tid * 2 + j;
                int r = unit >> 5, s = unit & 31;
                int g2 = tn * 32 + r;
                int4 z = {0, 0, 0, 0};
                p1[j] = (g2 < NN) ? *(const int4*)(A1 + (size_t)g2 * HH + s * 8) : z;
            }
        }
        __syncthreads();  // b1

        // hx0 = x @ W_node -> sHX
        {
            f4 acch[2][2];
            const f4 z4 = {0.f, 0.f, 0.f, 0.f};
#pragma unroll
            for (int rf = 0; rf < 2; ++rf)
#pragma unroll
                for (int n = 0; n < 2; ++n) acch[rf][n] = z4;
#pragma unroll
            for (int kb = 0; kb < 4; ++kb) {
                h8 a0 = *(const h8*)(sm + lm * 256 + SWZ(lm, kb * 64 + lg * 16));
                h8 a1 = *(const h8*)(sm + (16 + lm) * 256 + SWZ(16 + lm, kb * 64 + lg * 16));
#pragma unroll
                for (int n = 0; n < 2; ++n) {
                    acch[0][n] = __builtin_amdgcn_mfma_f32_16x16x32_f16(a0, wn[kb][n], acch[0][n], 0, 0, 0);
                    acch[1][n] = __builtin_amdgcn_mfma_f32_16x16x32_f16(a1, wn[kb][n], acch[1][n], 0, 0, 0);
                }
            }
#pragma unroll
            for (int rf = 0; rf < 2; ++rf)
#pragma unroll
                for (int n = 0; n < 2; ++n) {
                    int c2 = (w * 32 + n * 16 + lm) * 2;
#pragma unroll
                    for (int q = 0; q < 4; ++q) {
                        int r = rf * 16 + lg * 4 + q;
                        *(_Float16*)(sm + 24576 + r * 512 + SWZ(r, c2)) = (_Float16)acch[rf][n][q];
                    }
                }
        }
        __syncthreads();  // b2

        f4 acc[2][2];
        const f4 z4 = {0.f, 0.f, 0.f, 0.f};
#pragma unroll
        for (int rf = 0; rf < 2; ++rf)
#pragma unroll
            for (int n = 0; n < 2; ++n) acc[rf][n] = z4;

#pragma unroll
        for (int kb = 0; kb < 8; ++kb) {
            h8 a10 = *(const h8*)(sm + 8192 + lm * 512 + SWZ(lm, kb * 64 + lg * 16));
            h8 a11 = *(const h8*)(sm + 8192 + (16 + lm) * 512 + SWZ(16 + lm, kb * 64 + lg * 16));
            h8 a20 = *(const h8*)(sm + 24576 + lm * 512 + SWZ(lm, kb * 64 + lg * 16));
            h8 a21 = *(const h8*)(sm + 24576 + (16 + lm) * 512 + SWZ(16 + lm, kb * 64 + lg * 16));
#pragma unroll
            for (int n = 0; n < 2; ++n) {
                acc[0][n] = __builtin_amdgcn_mfma_f32_16x16x32_f16(a10, w1[kb][n], acc[0][n], 0, 0, 0);
                acc[1][n] = __builtin_amdgcn_mfma_f32_16x16x32_f16(a11, w1[kb][n], acc[1][n], 0, 0, 0);
                acc[0][n] = __builtin_amdgcn_mfma_f32_16x16x32_f16(a20, w2[kb][n], acc[0][n], 0, 0, 0);
                acc[1][n] = __builtin_amdgcn_mfma_f32_16x16x32_f16(a21, w2[kb][n], acc[1][n], 0, 0, 0);
            }
        }

        const int row0 = t * 32;
#pragma unroll
        for (int rf = 0; rf < 2; ++rf)
#pragma unroll
            for (int n = 0; n < 2; ++n) {
                const int col = w * 32 + n * 16 + lm;
#pragma unroll
                for (int q = 0; q < 4; ++q) {
                    int grow = row0 + rf * 16 + lg * 4 + q;
                    if (grow < NN) {
                        float v = fmaxf(acc[rf][n][q] + breg[n], 0.f);
                        C[(size_t)grow * HH + col] = (_Float16)v;
                    }
                }
            }
    }
}

// ---------------- BN fold + pack final weights into MFMA-B fragments ----------------
__global__ __launch_bounds__(256)
void k_bnprep(const float* __restrict__ stats, const float* __restrict__ gamma,
              const float* __restrict__ beta, const float* __restrict__ W_f2,
              const float* __restrict__ b_f2, _Float16* __restrict__ pWf,
              float* __restrict__ bfold) {
    __shared__ float sh[HH];
    __shared__ float ssc[HH];
    const int tid = threadIdx.x;
    const float invN = 1.0f / (float)NN;
    {
        float mu = stats[tid] * invN;
        float var = stats[HH + tid] * invN - mu * mu;
        float scale = gamma[tid] * rsqrtf(var + BN_EPS);
        sh[tid] = beta[tid] - mu * scale;
        ssc[tid] = scale;
    }
    __syncthreads();
    if (tid < CC) {
        float b = b_f2[tid];
        for (int k = 0; k < HH; ++k) b += sh[k] * W_f2[k * CC + tid];
        bfold[tid] = b;
    }
    const int w = tid >> 6, l = tid & 63;
    const int lm = l & 15, lg = l >> 4;
#pragma unroll
    for (int i = 0; i < 6; ++i) {
        int u = w + i * 4;  // 0..23
        int kb = u / 3, nb = u % 3;
        h8 hv;
#pragma unroll
        for (int j = 0; j < 8; ++j) {
            int k = kb * 32 + lg * 8 + j;
            int c = nb * 16 + lm;
            float v = (c < CC) ? ssc[k] * W_f2[k * CC + c] : 0.f;
            hv[j] = (_Float16)v;
        }
        *(h8*)(pWf + (size_t)u * 512 + l * 8) = hv;
    }
}

// ---------------- final via MFMA: out = h @ (scale*W_f2) + bfold ----------------
__global__ __launch_bounds__(256)
void k_finalM(const _Float16* __restrict__ h, const _Float16* __restrict__ pWf,
              const float* __restrict__ bfold, float* __restrict__ out) {
    __shared__ __align__(16) char sA[64 * 512];
    const int tid = threadIdx.x;
    const int w = tid >> 6, l = tid & 63;
    const int lm = l & 15, lg = l >> 4;

    h8 wreg[8][3];
#pragma unroll
    for (int kb = 0; kb < 8; ++kb)
#pragma unroll
        for (int nb = 0; nb < 3; ++nb)
            wreg[kb][nb] = *(const h8*)(pWf + (size_t)(kb * 3 + nb) * 512 + l * 8);

    const int row0 = blockIdx.x * 64;
#pragma unroll
    for (int j = 0; j < 8; ++j) {
        int unit = tid * 8 + j;
        int r = unit >> 5, s = unit & 31;
        int grow = row0 + r;
        int4 z = {0, 0, 0, 0};
        int4 v = (grow < NN) ? *(const int4*)(h + (size_t)grow * HH + s * 8) : z;
        *(int4*)(sA + r * 512 + SWZ(r, s * 16)) = v;
    }
    __syncthreads();

    f4 acc[3];
    const f4 z4 = {0.f, 0.f, 0.f, 0.f};
#pragma unroll
    for (int nb = 0; nb < 3; ++nb) acc[nb] = z4;

    const int ar = w * 16 + lm;
#pragma unroll
    for (int kb = 0; kb < 8; ++kb) {
        h8 a = *(const h8*)(sA + ar * 512 + SWZ(ar, kb * 64 + lg * 16));
#pragma unroll
        for (int nb = 0; nb < 3; ++nb)
            acc[nb] = __builtin_amdgcn_mfma_f32_16x16x32_f16(a, wreg[kb][nb], acc[nb], 0, 0, 0);
    }

#pragma unroll
    for (int nb = 0; nb < 3; ++nb) {
        int col = nb * 16 + lm;
        if (col < CC) {
            float bb = bfold[col];
#pragma unroll
            for (int q = 0; q < 4; ++q) {
                int grow = row0 + w * 16 + lg * 4 + q;
                if (grow < NN) out[(size_t)grow * CC + col] = acc[nb][q] + bb;
            }
        }
    }
}

extern "C" void kernel_launch(void* const* d_in, const int* in_sizes, int n_in,
                              void* d_out, int out_size, void* d_ws, size_t ws_size,
                              hipStream_t stream) {
    const float* x      = (const float*)d_in[0];
    const int*   ei     = (const int*)d_in[1];
    const float* ew     = (const float*)d_in[2];
    const float* W_edge = (const float*)d_in[3];
    const float* b_edge = (const float*)d_in[4];
    const float* W_node = (const float*)d_in[5];
    const float* b_node = (const float*)d_in[6];
    const float* W_c1   = (const float*)d_in[7];
    const float* b_c1   = (const float*)d_in[8];
    const float* W_c2   = (const float*)d_in[9];
    const float* b_c2   = (const float*)d_in[10];
    const float* W_f1   = (const float*)d_in[11];
    const float* b_f1   = (const float*)d_in[12];
    const float* gamma  = (const float*)d_in[13];
    const float* beta   = (const float*)d_in[14];
    const float* W_f2   = (const float*)d_in[15];
    const float* b_f2   = (const float*)d_in[16];
    float* out = (float*)d_out;

    const size_t NNH = (size_t)NN * HH;
    _Float16* bufA = (_Float16*)d_ws;            // h_a -> outB (in place)
    _Float16* bufH = bufA + NNH;                 // h
    _Float16* W16  = bufH + NNH;                 // fp16 W_edge
    unsigned int* esw = (unsigned int*)(W16 + NNH);  // E packed
    float* stats   = (float*)(esw + EE);         // 512
    float* bB      = stats + 2 * HH;             // 256
    float* bfold   = bB + HH;                    // 64
    _Float16* pWf  = (_Float16*)(bfold + 64);    // 24*512
    _Float16* pW   = pWf + 24 * 512;             // PW_HALVES
    int* deg       = (int*)(pW + PW_HALVES);     // N
    int* rowptr    = deg + NN;                   // N+1
    int* pos       = rowptr + NN + 1;            // N
    int* bsums     = pos + NN;                   // 256

    // zero stats (512 f32) and deg (N ints) via capturable async memsets
    hipMemsetAsync(stats, 0, 2 * HH * sizeof(float), stream);
    hipMemsetAsync(deg, 0, NN * sizeof(int), stream);

    k_prep<<<2048, 256, 0, stream>>>(W_edge, W16, ei, deg);
    k_pack<<<113, 256, 0, stream>>>(W_node, W_c1, W_c2, W_f1, b_node, b_c1, b_c2, pW, bB);
    k_scan1<<<196, 256, 0, stream>>>(deg, rowptr, bsums);
    k_scan2<<<1, 256, 0, stream>>>(bsums);
    k_scan3<<<196, 256, 0, stream>>>(rowptr, bsums, pos);
    k_ssort<<<(EE + 255) / 256, 256, 0, stream>>>(ei, ew, pos, esw);
    k_gather<<<12500, 256, 0, stream>>>(rowptr, esw, W16, b_edge, bufA);

    // GB2: outB = relu(h_a@(I+Wc1) + (x@Wn)@(I+Wc2) + bB) -> bufA (in place)
    k_gemmB2<<<256, 512, 0, stream>>>(x, bufA, pW, bB, bufA);
    // GC: h = relu(outB @ W_f1 + b_f1) + BN stats -> bufH
    k_gemm<8, 1><<<512, 256, 0, stream>>>(bufA, pW + OFF_F1, b_f1, bufH, stats);

    k_bnprep<<<1, 256, 0, stream>>>(stats, gamma, beta, W_f2, b_f2, pWf, bfold);
    k_finalM<<<(NN + 63) / 64, 256, 0, stream>>>(bufH, pWf, bfold, out);
}